// Round 8
// baseline (254.949 us; speedup 1.0000x reference)
//
#include <hip/hip_runtime.h>
#include <cstdint>
#include <cstddef>

// ---------------------------------------------------------------------------
// LSTM cell, B=8192, D=H=512, fp32 in/out.
// pre = [x|h] @ Wstack^T + bias ; gates -> c_t, h_t fused in GEMM epilogue.
// Round 8: NO LDS IN THE K-LOOP. R1-R7 (51-62us across 7 structures,
// barriered or not) showed the invariant bottleneck is the LDS pipe
// (~5.5 MB/CU through ~100 B/cyc). Both MFMA fragment layouts are contiguous
// 16B/lane chunks of the row-major global arrays, so A and B fragments load
// directly global->VGPR (global_load_dwordx4, L1/L2 serve the reuse).
// No staging, no barriers: 4 independent waves/block, 3 blocks/CU.
// R4's B-direct spill is avoided with __launch_bounds__(256,2) (256-reg cap).
// ---------------------------------------------------------------------------

typedef __attribute__((ext_vector_type(8))) short short8;   // 8 bf16 = 4 VGPRs
typedef __attribute__((ext_vector_type(4))) float floatx4;  // MFMA acc

__device__ __forceinline__ unsigned short f2bf(float f) {
  union { float f; unsigned u; } v; v.f = f;
  unsigned u = v.u;
  return (unsigned short)((u + 0x7fffu + ((u >> 16) & 1u)) >> 16);  // RNE
}

// --------------------------- pack everything -------------------------------
// blocks [0,8192):   A[b][k] = k<512 ? x[b][k] : h[b][k-512]      (8192x1024)
// blocks [8192,10240): B[n][k], n=gate*512+hh (f,i,g,o), k<512 -> Wx else Wh
//                      plus bias[n] = bx+bh at k==0.
struct PackArgs {
  const float* x; const float* h;
  const float* wx[4]; const float* wh[4];
  const float* bx[4]; const float* bh[4];
  unsigned short* A; unsigned short* B; float* bias;
};

__global__ __launch_bounds__(256) void pack_all_kernel(PackArgs P) {
  const int bid = blockIdx.x;
  if (bid < 8192) {
    int e = (bid * 256 + threadIdx.x) * 4;
    int b = e >> 10, k = e & 1023;
    const float* src = (k < 512) ? (P.x + b * 512 + k)
                                 : (P.h + b * 512 + (k - 512));
    float4 v = *(const float4*)src;
    ushort4 o;
    o.x = f2bf(v.x); o.y = f2bf(v.y); o.z = f2bf(v.z); o.w = f2bf(v.w);
    *(ushort4*)(P.A + e) = o;
  } else {
    int e = ((bid - 8192) * 256 + threadIdx.x) * 4;
    int n = e >> 10, k = e & 1023;
    int g = n >> 9, hh = n & 511;
    const float* src = (k < 512) ? (P.wx[g] + hh * 512 + k)
                                 : (P.wh[g] + hh * 512 + (k - 512));
    float4 v = *(const float4*)src;
    ushort4 o;
    o.x = f2bf(v.x); o.y = f2bf(v.y); o.z = f2bf(v.z); o.w = f2bf(v.w);
    *(ushort4*)(P.B + e) = o;
    if (k == 0) P.bias[n] = P.bx[g][hh] + P.bh[g][hh];
  }
}

// --------------------------- fused GEMM + LSTM epilogue --------------------
// Grid (64,16): tile = 128 batch x (4 gates x 32 hidden). K=1024.
// 256 threads = 4 waves; wave tile 64x64 (4x4 frags of 16x16x32 bf16).
// K-loop is pure global_load_dwordx4 + MFMA. LDS only for the epilogue.
__global__ __launch_bounds__(256, 2)
void lstm_gemm_kernel(const unsigned short* __restrict__ A,   // [8192][1024]
                      const unsigned short* __restrict__ B,   // [2048][1024]
                      const float* __restrict__ bias,         // [2048]
                      const float* __restrict__ c_prev,       // [8192][512]
                      float* __restrict__ h_out,              // [8192][512]
                      float* __restrict__ c_out) {            // [8192][512]
  __shared__ __align__(16) char smem[33792];  // epilogue: float[64][132]
  __shared__ float biasS[128];

  const int tid  = threadIdx.x;
  const int lane = tid & 63;
  const int w    = tid >> 6;        // wave 0..3
  const int quad = lane >> 4;
  const int colA = lane & 15;
  const int m0   = blockIdx.x * 128;
  const int h0   = blockIdx.y * 32;

  if (tid < 128) {
    biasS[tid] = bias[(tid >> 5) * 512 + h0 + (tid & 31)];
  }

  floatx4 acc[4][4];
#pragma unroll
  for (int i = 0; i < 4; ++i)
#pragma unroll
    for (int j = 0; j < 4; ++j) acc[i][j] = (floatx4){0.f, 0.f, 0.f, 0.f};

  const int wm = (w >> 1) * 64;     // wave M offset (0 or 64)
  const int wn = (w & 1) * 64;      // wave N' offset (0 or 64)

  // Per-lane fragment base pointers (16B chunks of global rows).
  // A frag (16x16x32): lane(quad,colA) holds A[row=colA][k=quad*8+j], j=0..7.
  const unsigned short* ap[4];
#pragma unroll
  for (int mi = 0; mi < 4; ++mi)
    ap[mi] = A + (size_t)(m0 + wm + mi * 16 + colA) * 1024 + quad * 8;
  // B frag: nn = wn + ni*16 + colA; global row = (nn>>5)*512 + h0 + (nn&31)
  // (gate-major stack). Verified correct in R4.
  const unsigned short* bp[4];
#pragma unroll
  for (int ni = 0; ni < 4; ++ni) {
    int nn = wn + ni * 16 + colA;
    int row = (nn >> 5) * 512 + h0 + (nn & 31);
    bp[ni] = B + (size_t)row * 1024 + quad * 8;
  }

  for (int kt = 0; kt < 16; ++kt) {
    const int kb = kt * 64;         // elements per row per kt (BK=64)
#pragma unroll
    for (int kk = 0; kk < 2; ++kk) {
      const int ko = kb + kk * 32;
      short8 af[4], bfr[4];
#pragma unroll
      for (int mi = 0; mi < 4; ++mi)
        af[mi] = *(const short8*)(ap[mi] + ko);
#pragma unroll
      for (int ni = 0; ni < 4; ++ni)
        bfr[ni] = *(const short8*)(bp[ni] + ko);
#pragma unroll
      for (int mi = 0; mi < 4; ++mi)
#pragma unroll
        for (int ni = 0; ni < 4; ++ni)
          acc[mi][ni] = __builtin_amdgcn_mfma_f32_16x16x32_bf16(
              af[mi], bfr[ni], acc[mi][ni], 0, 0, 0);
    }
  }

  // ------------------- fused epilogue (2 rounds of 64 M-rows) --------------
  __syncthreads();
  float* ep = (float*)smem;         // [64][132] padded
#pragma unroll
  for (int rd = 0; rd < 2; ++rd) {
    if ((w >> 1) == rd) {           // the 2 waves with wm == rd*64
      // C/D layout: row = quad*4 + rr, col = lane&15
#pragma unroll
      for (int mi = 0; mi < 4; ++mi)
#pragma unroll
        for (int ni = 0; ni < 4; ++ni) {
          int rr0 = mi * 16 + quad * 4;                 // 0..63
          int cc  = wn + ni * 16 + colA;                // 0..127
#pragma unroll
          for (int rr = 0; rr < 4; ++rr)
            ep[(rr0 + rr) * 132 + cc] = acc[mi][ni][rr];
        }
    }
    __syncthreads();
#pragma unroll
    for (int j = 0; j < 8; ++j) {
      int idx  = j * 256 + tid;     // 0..2047
      int mloc = idx >> 5;
      int hh   = idx & 31;
      float pf = ep[mloc * 132 +      hh] + biasS[hh];
      float pi = ep[mloc * 132 + 32 + hh] + biasS[32 + hh];
      float pg = ep[mloc * 132 + 64 + hh] + biasS[64 + hh];
      float po = ep[mloc * 132 + 96 + hh] + biasS[96 + hh];
      float fg = 1.f / (1.f + __expf(-pf));
      float ig = 1.f / (1.f + __expf(-pi));
      float gg = 1.f - 2.f / (1.f + __expf(2.f * pg));
      float og = 1.f / (1.f + __expf(-po));
      int m  = m0 + rd * 64 + mloc;
      int hg = h0 + hh;
      float cp = c_prev[m * 512 + hg];
      float cv = fg * cp + ig * gg;
      float th = 1.f - 2.f / (1.f + __expf(2.f * cv));
      h_out[m * 512 + hg] = og * th;
      c_out[m * 512 + hg] = cv;
    }
    __syncthreads();
  }
}

// ---------------------------------------------------------------------------
extern "C" void kernel_launch(void* const* d_in, const int* in_sizes, int n_in,
                              void* d_out, int out_size, void* d_ws, size_t ws_size,
                              hipStream_t stream) {
  // workspace: A_bf16 (16 MiB) | B_bf16 (4 MiB) | bias (8 KiB)
  char* ws = (char*)d_ws;
  unsigned short* Abf = (unsigned short*)ws;
  unsigned short* Bbf = (unsigned short*)(ws + (size_t)16777216);
  float* bias = (float*)(ws + (size_t)16777216 + 4194304);

  float* hout = (float*)d_out;
  float* cout = hout + (size_t)8192 * 512;

  PackArgs P;
  P.x = (const float*)d_in[0];
  P.h = (const float*)d_in[1];
  // gate order in stacked B: 0=f, 1=i, 2=g(cell), 3=o
  P.wx[0] = (const float*)d_in[3];  P.bx[0] = (const float*)d_in[4];
  P.wh[0] = (const float*)d_in[5];  P.bh[0] = (const float*)d_in[6];
  P.wx[1] = (const float*)d_in[7];  P.bx[1] = (const float*)d_in[8];
  P.wh[1] = (const float*)d_in[9];  P.bh[1] = (const float*)d_in[10];
  P.wx[2] = (const float*)d_in[11]; P.bx[2] = (const float*)d_in[12];
  P.wh[2] = (const float*)d_in[13]; P.bh[2] = (const float*)d_in[14];
  P.wx[3] = (const float*)d_in[15]; P.bx[3] = (const float*)d_in[16];
  P.wh[3] = (const float*)d_in[17]; P.bh[3] = (const float*)d_in[18];
  P.A = Abf; P.B = Bbf; P.bias = bias;

  pack_all_kernel<<<10240, 256, 0, stream>>>(P);

  const float* c = (const float*)d_in[2];
  dim3 grid(64, 16);
  lstm_gemm_kernel<<<grid, 256, 0, stream>>>(Abf, Bbf, bias, c, hout, cout);
}